// Round 2
// baseline (3212.534 us; speedup 1.0000x reference)
//
#include <hip/hip_runtime.h>

#define DEV __device__ __forceinline__

// monotone float<->uint encoding for atomicMax on floats (handles negatives)
DEV unsigned fenc(float f) {
    unsigned b = __float_as_uint(f);
    return (b & 0x80000000u) ? ~b : (b | 0x80000000u);
}
DEV float fdec(unsigned u) {
    unsigned b = (u & 0x80000000u) ? (u ^ 0x80000000u) : ~u;
    return __uint_as_float(b);
}
static constexpr unsigned ENC_NEG_INF = 0x007FFFFFu; // fenc(-inf)

__global__ void k_fill(unsigned* p, int n, unsigned v) {
    int i = blockIdx.x * blockDim.x + threadIdx.x;
    if (i < n) p[i] = v;
}

// out[row, c] = bias[c] + sum_k A[row,k] * W[k,c]   (block = M threads, one row per block)
template <int K, int M>
__global__ void k_gemm(const float* __restrict__ A, const float* __restrict__ W,
                       const float* __restrict__ bias, float* __restrict__ out, int N) {
    __shared__ float arow[K];
    int row = blockIdx.x;
    int c = threadIdx.x;
    for (int i = c; i < K; i += M) arow[i] = A[(size_t)row * K + i];
    __syncthreads();
    float acc = bias[c];
#pragma unroll 8
    for (int k = 0; k < K; k++) acc += arow[k] * W[k * M + c];
    out[(size_t)row * M + c] = acc;
}

// Per edge: logit[e,h] = sum_c att[h,c] * leakyrelu(xl[src,c] + xr[dst,c] + (ea @ We)[c])
// 64 lanes per edge, 4 edges per 256-thread block. atomicMax per-dst max.
template <int H, int C>
__global__ void k_edge_logit(const float* __restrict__ xl, const float* __restrict__ xr,
                             const float* __restrict__ ea,
                             const float* __restrict__ We,
                             const float* __restrict__ att,
                             const int* __restrict__ ei, int E,
                             float* __restrict__ logits, unsigned* __restrict__ maxb) {
    constexpr int HC = H * C;
    __shared__ float sWe[32 * HC];
    __shared__ float sAtt[HC];
    int tid = threadIdx.x;
    for (int i = tid; i < 32 * HC; i += 256) sWe[i] = We[i];
    for (int i = tid; i < HC; i += 256) sAtt[i] = att[i];
    __syncthreads();
    int g = tid >> 6, lane = tid & 63;
    int e = blockIdx.x * 4 + g;
    if (e >= E) return;
    int src = ei[e], dst = ei[E + e];
    float eav[32];
    const float* eap = ea + (size_t)e * 32;
#pragma unroll
    for (int k = 0; k < 32; k++) eav[k] = eap[k];
    const float* xls = xl + (size_t)src * HC;
    const float* xrd = xr + (size_t)dst * HC;
    float p0 = 0.f, p1 = 0.f;
    {
        int c = lane;
        float eec = 0.f;
#pragma unroll
        for (int k = 0; k < 32; k++) eec += eav[k] * sWe[k * HC + c];
        float v = xls[c] + xrd[c] + eec;
        v = v > 0.f ? v : 0.2f * v;
        p0 = sAtt[c] * v;
    }
    if constexpr (HC == 128) {
        int c = lane + 64;
        float eec = 0.f;
#pragma unroll
        for (int k = 0; k < 32; k++) eec += eav[k] * sWe[k * HC + c];
        float v = xls[c] + xrd[c] + eec;
        v = v > 0.f ? v : 0.2f * v;
        p1 = sAtt[c] * v;
    }
#pragma unroll
    for (int m = 32; m; m >>= 1) {
        p0 += __shfl_xor(p0, m);
        if constexpr (H == 2) p1 += __shfl_xor(p1, m);
    }
    if (lane == 0) {
        logits[(size_t)e * H + 0] = p0;
        atomicMax(&maxb[dst * H + 0], fenc(p0));
        if constexpr (H == 2) {
            logits[(size_t)e * H + 1] = p1;
            atomicMax(&maxb[dst * H + 1], fenc(p1));
        }
    }
}

template <int H>
__global__ void k_edge_exp(float* __restrict__ logits, const int* __restrict__ ei, int E,
                           const unsigned* __restrict__ maxb, float* __restrict__ denom) {
    int i = blockIdx.x * blockDim.x + threadIdx.x;
    if (i >= E * H) return;
    int e = i / H, h = i - e * H;
    int dst = ei[E + e];
    float m = fdec(maxb[dst * H + h]);
    float ex = expf(logits[i] - m);
    atomicAdd(&denom[dst * H + h], ex);
    logits[i] = ex;
}

template <int H, int C>
__global__ void k_edge_agg(const float* __restrict__ xl, const float* __restrict__ ex,
                           const float* __restrict__ denom, const int* __restrict__ ei, int E,
                           float* __restrict__ outb) {
    constexpr int HC = H * C;
    int tid = threadIdx.x;
    int g = tid >> 6, lane = tid & 63;
    int e = blockIdx.x * 4 + g;
    if (e >= E) return;
    int src = ei[e], dst = ei[E + e];
    float a0 = ex[(size_t)e * H + 0] / (denom[dst * H + 0] + 1e-16f);
    const float* xls = xl + (size_t)src * HC;
    float* od = outb + (size_t)dst * HC;
    atomicAdd(&od[lane], a0 * xls[lane]);
    if constexpr (HC == 128) {
        float a1 = ex[(size_t)e * H + 1] / (denom[dst * H + 1] + 1e-16f);
        atomicAdd(&od[lane + 64], a1 * xls[lane + 64]);
    }
}

template <bool RELU, int M>
__global__ void k_bias_act(const float* __restrict__ in, const float* __restrict__ bias,
                           float* __restrict__ out, int total) {
    int i = blockIdx.x * blockDim.x + threadIdx.x;
    if (i >= total) return;
    float v = in[i] + bias[i & (M - 1)];
    if (RELU) v = v > 0.f ? v : 0.f;
    out[i] = v;
}

// gate[n] = (relu(h[n] @ G1w + G1b) @ G2w + G2b); atomicMax per-graph max
__global__ void k_gate(const float* __restrict__ h, const float* __restrict__ G1w,
                       const float* __restrict__ G1b, const float* __restrict__ G2w,
                       const float* __restrict__ G2b, const int* __restrict__ batch,
                       float* __restrict__ gate, unsigned* __restrict__ gmaxb, int N) {
    __shared__ float hr[64];
    __shared__ float part[2];
    int n = blockIdx.x;
    int t = threadIdx.x;
    if (t < 64) hr[t] = h[(size_t)n * 64 + t];
    __syncthreads();
    float acc = G1b[t];
#pragma unroll 8
    for (int k = 0; k < 64; k++) acc += hr[k] * G1w[k * 128 + t];
    acc = acc > 0.f ? acc : 0.f;
    float p = acc * G2w[t];
#pragma unroll
    for (int m = 32; m; m >>= 1) p += __shfl_xor(p, m);
    if ((t & 63) == 0) part[t >> 6] = p;
    __syncthreads();
    if (t == 0) {
        float gv = part[0] + part[1] + G2b[0];
        gate[n] = gv;
        atomicMax(&gmaxb[batch[n]], fenc(gv));
    }
}

__global__ void k_gexp(float* __restrict__ gate, const int* __restrict__ batch,
                       const unsigned* __restrict__ gmaxb, float* __restrict__ gden, int N) {
    int n = blockIdx.x * blockDim.x + threadIdx.x;
    if (n >= N) return;
    int g = batch[n];
    float ex = expf(gate[n] - fdec(gmaxb[g]));
    atomicAdd(&gden[g], ex);
    gate[n] = ex;
}

__global__ void k_pool(const float* __restrict__ h, const float* __restrict__ gate,
                       const float* __restrict__ gden, const int* __restrict__ batch,
                       float* __restrict__ pooled, int N) {
    int tid = threadIdx.x;
    int g4 = tid >> 6, lane = tid & 63;
    int n = blockIdx.x * 4 + g4;
    if (n >= N) return;
    int b = batch[n];
    float w = gate[n] / (gden[b] + 1e-16f);
    atomicAdd(&pooled[b * 64 + lane], w * h[(size_t)n * 64 + lane]);
}

__global__ void k_final(const float* __restrict__ pooled, const float* __restrict__ Wreg,
                        const float* __restrict__ breg, float* __restrict__ out) {
    int g = threadIdx.x;
    float acc = breg[0];
    for (int c = 0; c < 64; c++) acc += pooled[g * 64 + c] * Wreg[c];
    out[g] = acc;
}

extern "C" void kernel_launch(void* const* d_in, const int* in_sizes, int n_in,
                              void* d_out, int out_size, void* d_ws, size_t ws_size,
                              hipStream_t stream) {
    const float* x  = (const float*)d_in[0];
    const float* ea = (const float*)d_in[1];
    const int* ei    = (const int*)d_in[2];
    const int* batch = (const int*)d_in[3];
    auto ff = [&](int i) { return (const float*)d_in[i]; };
    const float *W1l = ff(4), *b1l = ff(5), *W1r = ff(6), *b1r = ff(7), *W1e = ff(8),
                *att1 = ff(9), *bias1 = ff(10);
    const float *W2l = ff(11), *b2l = ff(12), *W2r = ff(13), *b2r = ff(14), *W2e = ff(15),
                *att2 = ff(16), *bias2 = ff(17);
    const float *W3l = ff(18), *b3l = ff(19), *W3r = ff(20), *b3r = ff(21), *W3e = ff(22),
                *att3 = ff(23), *bias3 = ff(24);
    const float *G1w = ff(25), *G1b = ff(26), *G2w = ff(27), *G2b = ff(28), *Wreg = ff(29),
                *breg = ff(30);

    const int N = in_sizes[0] / 128;      // 40000
    const int E = in_sizes[2] / 2;        // 640000

    char* ws = (char*)d_ws;
    float*    bufA   = (float*)(ws);                 // [N,128] xl
    float*    bufB   = (float*)(ws + 20480000);      // [N,128] xr; bufO aliases (xr dead after logit)
    float*    bufO   = bufB;                         // [N,128] aggregation output
    float*    bufH   = (float*)(ws + 40960000);      // [N,128] layer io
    float*    logits = (float*)(ws + 61440000);      // [E,2]
    float*    denom  = (float*)(ws + 66560000);      // [N,2]
    unsigned* maxb   = (unsigned*)(ws + 66880000);   // [N,2]
    float*    gate   = (float*)(ws + 67200000);      // [N]
    unsigned* gmaxb  = (unsigned*)(ws + 67360000);   // [64]
    float*    gden   = (float*)(ws + 67360256);      // [64]   (contiguous with pooled)
    float*    pooled = (float*)(ws + 67360512);      // [64,64]

    const int EB = (E + 3) / 4;       // edge blocks (256 thr, 4 edges)
    auto cdiv = [](int a, int b) { return (a + b - 1) / b; };

    // ---------------- layer 1: x(f32,128) -> H=2,C=64 ----------------
    k_gemm<128, 128><<<N, 128, 0, stream>>>(x, W1l, b1l, bufA, N);
    k_gemm<128, 128><<<N, 128, 0, stream>>>(x, W1r, b1r, bufB, N);
    k_fill<<<cdiv(N * 2, 256), 256, 0, stream>>>(maxb, N * 2, ENC_NEG_INF);
    k_fill<<<cdiv(N * 2, 256), 256, 0, stream>>>((unsigned*)denom, N * 2, 0u);
    k_edge_logit<2, 64><<<EB, 256, 0, stream>>>(bufA, bufB, ea, W1e, att1, ei, E, logits, maxb);
    k_fill<<<cdiv(N * 128, 256), 256, 0, stream>>>((unsigned*)bufO, N * 128, 0u);  // after logit: bufO==bufB
    k_edge_exp<2><<<cdiv(E * 2, 256), 256, 0, stream>>>(logits, ei, E, maxb, denom);
    k_edge_agg<2, 64><<<EB, 256, 0, stream>>>(bufA, logits, denom, ei, E, bufO);
    k_bias_act<true, 128><<<cdiv(N * 128, 256), 256, 0, stream>>>(bufO, bias1, bufH, N * 128);

    // ---------------- layer 2: bufH(f32,128) -> H=2,C=64 ----------------
    k_gemm<128, 128><<<N, 128, 0, stream>>>(bufH, W2l, b2l, bufA, N);
    k_gemm<128, 128><<<N, 128, 0, stream>>>(bufH, W2r, b2r, bufB, N);
    k_fill<<<cdiv(N * 2, 256), 256, 0, stream>>>(maxb, N * 2, ENC_NEG_INF);
    k_fill<<<cdiv(N * 2, 256), 256, 0, stream>>>((unsigned*)denom, N * 2, 0u);
    k_edge_logit<2, 64><<<EB, 256, 0, stream>>>(bufA, bufB, ea, W2e, att2, ei, E, logits, maxb);
    k_fill<<<cdiv(N * 128, 256), 256, 0, stream>>>((unsigned*)bufO, N * 128, 0u);
    k_edge_exp<2><<<cdiv(E * 2, 256), 256, 0, stream>>>(logits, ei, E, maxb, denom);
    k_edge_agg<2, 64><<<EB, 256, 0, stream>>>(bufA, logits, denom, ei, E, bufO);
    k_bias_act<true, 128><<<cdiv(N * 128, 256), 256, 0, stream>>>(bufO, bias2, bufH, N * 128);

    // ---------------- layer 3: bufH(f32,128) -> H=1,C=64 ----------------
    k_gemm<128, 64><<<N, 64, 0, stream>>>(bufH, W3l, b3l, bufA, N);
    k_gemm<128, 64><<<N, 64, 0, stream>>>(bufH, W3r, b3r, bufB, N);
    k_fill<<<cdiv(N, 256), 256, 0, stream>>>(maxb, N, ENC_NEG_INF);
    k_fill<<<cdiv(N, 256), 256, 0, stream>>>((unsigned*)denom, N, 0u);
    k_edge_logit<1, 64><<<EB, 256, 0, stream>>>(bufA, bufB, ea, W3e, att3, ei, E, logits, maxb);
    k_fill<<<cdiv(N * 64, 256), 256, 0, stream>>>((unsigned*)bufO, N * 64, 0u);
    k_edge_exp<1><<<cdiv(E, 256), 256, 0, stream>>>(logits, ei, E, maxb, denom);
    k_edge_agg<1, 64><<<EB, 256, 0, stream>>>(bufA, logits, denom, ei, E, bufO);
    k_bias_act<false, 64><<<cdiv(N * 64, 256), 256, 0, stream>>>(bufO, bias3, bufH, N * 64);

    // ---------------- attentional aggregation + regressor ----------------
    k_fill<<<1, 64, 0, stream>>>(gmaxb, 64, ENC_NEG_INF);
    k_fill<<<cdiv(64 + 64 * 64, 256), 256, 0, stream>>>((unsigned*)gden, 64 + 64 * 64, 0u);
    k_gate<<<N, 128, 0, stream>>>(bufH, G1w, G1b, G2w, G2b, batch, gate, gmaxb, N);
    k_gexp<<<cdiv(N, 256), 256, 0, stream>>>(gate, batch, gmaxb, gden, N);
    k_pool<<<cdiv(N, 4), 256, 0, stream>>>(bufH, gate, gden, batch, pooled, N);
    k_final<<<1, 64, 0, stream>>>(pooled, Wreg, breg, (float*)d_out);
}

// Round 3
// 1918.493 us; speedup vs baseline: 1.6745x; 1.6745x over previous
//
#include <hip/hip_runtime.h>

#define DEV __device__ __forceinline__

__global__ void k_fill(unsigned* p, int n, unsigned v) {
    int i = blockIdx.x * blockDim.x + threadIdx.x;
    if (i < n) p[i] = v;
}

// Dual GEMM: out{l,r}[row,c] = bias{l,r}[c] + sum_k A[row,k]*W{l,r}[k,c]
// K=128 fixed. Block computes 64 rows x M cols; blockIdx.y selects l/r.
// RW rows x 4 cols per thread. M=128 -> RW=8, M=64 -> RW=4.
template <int M, int RW>
__global__ __launch_bounds__(256) void k_gemm2(const float* __restrict__ A,
                                               const float* __restrict__ Wl, const float* __restrict__ bl,
                                               const float* __restrict__ Wr, const float* __restrict__ br,
                                               float* __restrict__ outl, float* __restrict__ outr) {
    constexpr int TX = M / 4;          // threads across cols
    __shared__ float sA[32][68];       // [k][row], pad 68 for write-bank spread
    __shared__ float sW[32][M];
    const float* W    = blockIdx.y ? Wr : Wl;
    const float* bias = blockIdx.y ? br : bl;
    float* out        = blockIdx.y ? outr : outl;
    int t = threadIdx.x;
    int tx = t % TX, ty = t / TX;
    int r0 = blockIdx.x * 64;
    float acc[RW][4] = {};
    for (int kt = 0; kt < 128; kt += 32) {
        for (int l = t; l < 512; l += 256) {           // A tile: 64 rows x 32 k, as float4
            int row = l >> 3, kq = (l & 7) << 2;
            float4 a = *(const float4*)&A[(size_t)(r0 + row) * 128 + kt + kq];
            sA[kq + 0][row] = a.x; sA[kq + 1][row] = a.y;
            sA[kq + 2][row] = a.z; sA[kq + 3][row] = a.w;
        }
        for (int l = t; l < 32 * M / 4; l += 256) {    // W tile: 32 k x M
            int kk = (l * 4) / M, cc = (l * 4) % M;
            *(float4*)&sW[kk][cc] = *(const float4*)&W[(size_t)(kt + kk) * M + cc];
        }
        __syncthreads();
#pragma unroll
        for (int k = 0; k < 32; k++) {
            float4 w = *(float4*)&sW[k][tx * 4];
            float ar[RW];
#pragma unroll
            for (int i = 0; i < RW; i += 4) {
                float4 a = *(float4*)&sA[k][ty * RW + i];
                ar[i] = a.x; ar[i + 1] = a.y; ar[i + 2] = a.z; ar[i + 3] = a.w;
            }
#pragma unroll
            for (int i = 0; i < RW; i++) {
                acc[i][0] += ar[i] * w.x; acc[i][1] += ar[i] * w.y;
                acc[i][2] += ar[i] * w.z; acc[i][3] += ar[i] * w.w;
            }
        }
        __syncthreads();
    }
    float4 b = *(const float4*)&bias[tx * 4];
#pragma unroll
    for (int i = 0; i < RW; i++) {
        float4 v;
        v.x = acc[i][0] + b.x; v.y = acc[i][1] + b.y;
        v.z = acc[i][2] + b.z; v.w = acc[i][3] + b.w;
        *(float4*)&out[(size_t)(r0 + ty * RW + i) * M + tx * 4] = v;
    }
}

// Fused per-edge pass: ee = ea@We (per-lane registers), logit via shuffle-reduce,
// ex = exp(logit) (max-subtraction skipped: logits bounded, softmax ratio exact),
// atomicAdd denom[dst,h] and out[dst,:] += ex * xl[src,:].
// One wave per edge, 4 waves/block, EPB edges per block.
template <int H, int C, int EPB>
__global__ __launch_bounds__(256) void k_edge_fused(const float* __restrict__ xl, const float* __restrict__ xr,
                                                    const float* __restrict__ ea, const float* __restrict__ We,
                                                    const float* __restrict__ att, const int* __restrict__ ei,
                                                    int E, float* __restrict__ denom, float* __restrict__ outb) {
    constexpr int HC = H * C;
    int tid = threadIdx.x;
    int wv = tid >> 6, lane = tid & 63;
    // lane owns columns c0=lane (head 0) and c1=64+lane (head 1)
    float rWe0[32], rWe1[H == 2 ? 32 : 1];
#pragma unroll
    for (int k = 0; k < 32; k++) rWe0[k] = We[k * HC + lane];
    if constexpr (H == 2) {
#pragma unroll
        for (int k = 0; k < 32; k++) rWe1[k] = We[k * HC + 64 + lane];
    }
    float att0 = att[lane];
    float att1 = (H == 2) ? att[64 + lane] : 0.f;
    int e0 = blockIdx.x * EPB + wv;
    for (int it = 0; it < EPB; it += 4) {
        int e = e0 + it;
        if (e >= E) break;
        int src = ei[e], dst = ei[E + e];
        const float4* eap = (const float4*)(ea + (size_t)e * 32);
        const float* xls = xl + (size_t)src * HC;
        const float* xrd = xr + (size_t)dst * HC;
        float xl0 = xls[lane], xr0 = xrd[lane];
        float xl1 = 0.f, xr1 = 0.f;
        if constexpr (H == 2) { xl1 = xls[64 + lane]; xr1 = xrd[64 + lane]; }
        float ee0 = 0.f, ee1 = 0.f;
#pragma unroll
        for (int kq = 0; kq < 8; kq++) {
            float4 v = eap[kq];
            ee0 += v.x * rWe0[kq * 4 + 0]; ee0 += v.y * rWe0[kq * 4 + 1];
            ee0 += v.z * rWe0[kq * 4 + 2]; ee0 += v.w * rWe0[kq * 4 + 3];
            if constexpr (H == 2) {
                ee1 += v.x * rWe1[kq * 4 + 0]; ee1 += v.y * rWe1[kq * 4 + 1];
                ee1 += v.z * rWe1[kq * 4 + 2]; ee1 += v.w * rWe1[kq * 4 + 3];
            }
        }
        float v0 = xl0 + xr0 + ee0;
        v0 = v0 > 0.f ? v0 : 0.2f * v0;
        float p0 = att0 * v0;
        float p1 = 0.f;
        if constexpr (H == 2) {
            float v1 = xl1 + xr1 + ee1;
            v1 = v1 > 0.f ? v1 : 0.2f * v1;
            p1 = att1 * v1;
        }
#pragma unroll
        for (int m = 32; m; m >>= 1) {
            p0 += __shfl_xor(p0, m);
            if constexpr (H == 2) p1 += __shfl_xor(p1, m);
        }
        float ex0 = __expf(p0);
        float ex1 = (H == 2) ? __expf(p1) : 0.f;
        if (lane == 0) atomicAdd(&denom[dst * H + 0], ex0);
        if constexpr (H == 2) {
            if (lane == 1) atomicAdd(&denom[dst * H + 1], ex1);
        }
        float* od = outb + (size_t)dst * HC;
        atomicAdd(&od[lane], ex0 * xl0);
        if constexpr (H == 2) atomicAdd(&od[64 + lane], ex1 * xl1);
    }
}

// out[n,hc] = act( in[n,hc] / denom[n,h] + bias[hc] )
template <bool RELU, int H, int C>
__global__ void k_bias_div_act(const float* __restrict__ in, const float* __restrict__ denom,
                               const float* __restrict__ bias, float* __restrict__ out, int total) {
    constexpr int HC = H * C;
    int i = blockIdx.x * blockDim.x + threadIdx.x;
    if (i >= total) return;
    int n = i / HC, hc = i - n * HC;
    int h = hc >> 6;
    float d = denom[n * H + h] + 1e-16f;
    float v = in[i] / d + bias[hc];
    if (RELU) v = v > 0.f ? v : 0.f;
    out[i] = v;
}

// gate[n] = exp( relu(h[n]@G1w+G1b)@G2w + G2b ); atomicAdd per-graph denom.
// 8 nodes per block (2 concurrently across the 256 threads).
__global__ __launch_bounds__(256) void k_gate(const float* __restrict__ h, const float* __restrict__ G1w,
                                              const float* __restrict__ G1b, const float* __restrict__ G2w,
                                              const float* __restrict__ G2b, const int* __restrict__ batch,
                                              float* __restrict__ gate, float* __restrict__ gden, int N) {
    __shared__ float hr[8][64];
    __shared__ float part[8][2];
    int t = threadIdx.x;
    int n0 = blockIdx.x * 8;
    for (int l = t; l < 8 * 64; l += 256)
        hr[l >> 6][l & 63] = h[(size_t)(n0 + (l >> 6)) * 64 + (l & 63)];
    __syncthreads();
    int c = t & 127, half = t >> 7;
    for (int np = 0; np < 8; np += 2) {
        int n = np + half;
        float acc = G1b[c];
#pragma unroll 8
        for (int k = 0; k < 64; k++) acc += hr[n][k] * G1w[k * 128 + c];
        acc = acc > 0.f ? acc : 0.f;
        float p = acc * G2w[c];
#pragma unroll
        for (int m = 32; m; m >>= 1) p += __shfl_xor(p, m);
        if ((t & 63) == 0) part[n][(t >> 6) & 1] = p;
        __syncthreads();
        if (t < 2) {
            int nn = np + t;
            float gv = __expf(part[nn][0] + part[nn][1] + G2b[0]);
            gate[n0 + nn] = gv;
            atomicAdd(&gden[batch[n0 + nn]], gv);
        }
        __syncthreads();
    }
}

__global__ void k_pool(const float* __restrict__ h, const float* __restrict__ gate,
                       const float* __restrict__ gden, const int* __restrict__ batch,
                       float* __restrict__ pooled, int N) {
    int tid = threadIdx.x;
    int g4 = tid >> 6, lane = tid & 63;
    int n = blockIdx.x * 4 + g4;
    if (n >= N) return;
    int b = batch[n];
    float w = gate[n] / (gden[b] + 1e-16f);
    atomicAdd(&pooled[b * 64 + lane], w * h[(size_t)n * 64 + lane]);
}

__global__ void k_final(const float* __restrict__ pooled, const float* __restrict__ Wreg,
                        const float* __restrict__ breg, float* __restrict__ out) {
    int g = threadIdx.x;
    float acc = breg[0];
    for (int c = 0; c < 64; c++) acc += pooled[g * 64 + c] * Wreg[c];
    out[g] = acc;
}

extern "C" void kernel_launch(void* const* d_in, const int* in_sizes, int n_in,
                              void* d_out, int out_size, void* d_ws, size_t ws_size,
                              hipStream_t stream) {
    const float* x  = (const float*)d_in[0];
    const float* ea = (const float*)d_in[1];
    const int* ei    = (const int*)d_in[2];
    const int* batch = (const int*)d_in[3];
    auto ff = [&](int i) { return (const float*)d_in[i]; };
    const float *W1l = ff(4), *b1l = ff(5), *W1r = ff(6), *b1r = ff(7), *W1e = ff(8),
                *att1 = ff(9), *bias1 = ff(10);
    const float *W2l = ff(11), *b2l = ff(12), *W2r = ff(13), *b2r = ff(14), *W2e = ff(15),
                *att2 = ff(16), *bias2 = ff(17);
    const float *W3l = ff(18), *b3l = ff(19), *W3r = ff(20), *b3r = ff(21), *W3e = ff(22),
                *att3 = ff(23), *bias3 = ff(24);
    const float *G1w = ff(25), *G1b = ff(26), *G2w = ff(27), *G2b = ff(28), *Wreg = ff(29),
                *breg = ff(30);

    const int N = in_sizes[0] / 128;  // 40000
    const int E = in_sizes[2] / 2;    // 640000

    char* ws = (char*)d_ws;
    float* bufA   = (float*)(ws);                // [N,128] xl
    float* bufB   = (float*)(ws + 20480000);     // [N,128] xr
    float* bufO   = (float*)(ws + 40960000);     // [N,128] aggregation (denom follows contiguously)
    float* denom  = (float*)(ws + 61440000);     // [N,2]
    float* bufH   = (float*)(ws + 61760000);     // [N,128] layer io
    float* gate   = (float*)(ws + 82240000);     // [N]
    float* gden   = (float*)(ws + 82400000);     // [64] (pooled follows contiguously)
    float* pooled = (float*)(ws + 82400256);     // [64,64]

    auto cdiv = [](int a, int b) { return (a + b - 1) / b; };
    const int EBLK = cdiv(E, 64);                // edge blocks, 64 edges each
    const dim3 gemmG(N / 64, 2);

    // ---------------- layer 1: x -> H=2,C=64 ----------------
    k_gemm2<128, 8><<<gemmG, 256, 0, stream>>>(x, W1l, b1l, W1r, b1r, bufA, bufB);
    k_fill<<<cdiv(N * 130, 256), 256, 0, stream>>>((unsigned*)bufO, N * 130, 0u);  // bufO + denom
    k_edge_fused<2, 64, 64><<<EBLK, 256, 0, stream>>>(bufA, bufB, ea, W1e, att1, ei, E, denom, bufO);
    k_bias_div_act<true, 2, 64><<<cdiv(N * 128, 256), 256, 0, stream>>>(bufO, denom, bias1, bufH, N * 128);

    // ---------------- layer 2: bufH -> H=2,C=64 ----------------
    k_gemm2<128, 8><<<gemmG, 256, 0, stream>>>(bufH, W2l, b2l, W2r, b2r, bufA, bufB);
    k_fill<<<cdiv(N * 130, 256), 256, 0, stream>>>((unsigned*)bufO, N * 130, 0u);
    k_edge_fused<2, 64, 64><<<EBLK, 256, 0, stream>>>(bufA, bufB, ea, W2e, att2, ei, E, denom, bufO);
    k_bias_div_act<true, 2, 64><<<cdiv(N * 128, 256), 256, 0, stream>>>(bufO, denom, bias2, bufH, N * 128);

    // ---------------- layer 3: bufH -> H=1,C=64 ----------------
    k_gemm2<64, 4><<<gemmG, 256, 0, stream>>>(bufH, W3l, b3l, W3r, b3r, bufA, bufB);
    k_fill<<<cdiv(N * 130, 256), 256, 0, stream>>>((unsigned*)bufO, N * 130, 0u);
    k_edge_fused<1, 64, 64><<<EBLK, 256, 0, stream>>>(bufA, bufB, ea, W3e, att3, ei, E, denom, bufO);
    k_bias_div_act<false, 1, 64><<<cdiv(N * 64, 256), 256, 0, stream>>>(bufO, denom, bias3, bufH, N * 64);

    // ---------------- attentional aggregation + regressor ----------------
    k_fill<<<cdiv(64 + 64 * 64, 256), 256, 0, stream>>>((unsigned*)gden, 64 + 64 * 64, 0u);
    k_gate<<<N / 8, 256, 0, stream>>>(bufH, G1w, G1b, G2w, G2b, batch, gate, gden, N);
    k_pool<<<cdiv(N, 4), 256, 0, stream>>>(bufH, gate, gden, batch, pooled, N);
    k_final<<<1, 64, 0, stream>>>(pooled, Wreg, breg, (float*)d_out);
}

// Round 4
// 1540.768 us; speedup vs baseline: 2.0850x; 1.2452x over previous
//
#include <hip/hip_runtime.h>

__global__ void k_fill(unsigned* p, int n, unsigned v) {
    int i = blockIdx.x * blockDim.x + threadIdx.x;
    if (i < n) p[i] = v;
}

// ---------------- CSR build (graph identical across layers; built once) ----------------
__global__ void k_hist(const int* __restrict__ ei, int E, int* __restrict__ deg) {
    int e = blockIdx.x * blockDim.x + threadIdx.x;
    if (e < E) atomicAdd(&deg[ei[E + e]], 1);
}

// exclusive scan, two-level (N <= 256*256)
__global__ void k_scan_blocks(const int* __restrict__ deg, int N,
                              int* __restrict__ excl, int* __restrict__ parts) {
    __shared__ int s[256];
    int t = threadIdx.x, i = blockIdx.x * 256 + t;
    int v = (i < N) ? deg[i] : 0;
    s[t] = v;
    __syncthreads();
    int acc = v;
    for (int off = 1; off < 256; off <<= 1) {
        int add = (t >= off) ? s[t - off] : 0;
        __syncthreads();
        acc += add;
        s[t] = acc;
        __syncthreads();
    }
    if (i < N) excl[i] = acc - v;
    if (t == 255) parts[blockIdx.x] = acc;
}

__global__ void k_scan_parts(int* __restrict__ parts, int nb) {
    __shared__ int s[256];
    int t = threadIdx.x;
    int v = (t < nb) ? parts[t] : 0;
    s[t] = v;
    __syncthreads();
    int acc = v;
    for (int off = 1; off < 256; off <<= 1) {
        int add = (t >= off) ? s[t - off] : 0;
        __syncthreads();
        acc += add;
        s[t] = acc;
        __syncthreads();
    }
    if (t < nb) parts[t] = acc - v;  // exclusive of block sums
}

__global__ void k_scan_add(const int* __restrict__ excl, const int* __restrict__ parts,
                           int* __restrict__ row_ptr, int* __restrict__ cursor, int N) {
    int i = blockIdx.x * blockDim.x + threadIdx.x;
    if (i >= N) return;
    int r = excl[i] + parts[i >> 8];
    row_ptr[i] = r;
    cursor[i] = r;
}

__global__ void k_scatter(const int* __restrict__ ei, int E, int* __restrict__ cursor,
                          int2* __restrict__ elist) {
    int e = blockIdx.x * blockDim.x + threadIdx.x;
    if (e >= E) return;
    int d = ei[E + e];
    int j = atomicAdd(&cursor[d], 1);
    elist[j] = make_int2(ei[e], e);  // (src, original edge id)
}

// ---------------- Dual GEMM: out{l,r} = A @ W{l,r} + b{l,r} ----------------
// K=128 fixed. Block = 64 rows x M cols; blockIdx.y selects l/r. RW rows x 4 cols / thread.
template <int M, int RW>
__global__ __launch_bounds__(256) void k_gemm2(const float* __restrict__ A,
                                               const float* __restrict__ Wl, const float* __restrict__ bl,
                                               const float* __restrict__ Wr, const float* __restrict__ br,
                                               float* __restrict__ outl, float* __restrict__ outr) {
    constexpr int TX = M / 4;
    __shared__ float sA[32][68];
    __shared__ float sW[32][M];
    const float* W    = blockIdx.y ? Wr : Wl;
    const float* bias = blockIdx.y ? br : bl;
    float* out        = blockIdx.y ? outr : outl;
    int t = threadIdx.x;
    int tx = t % TX, ty = t / TX;
    int r0 = blockIdx.x * 64;
    float acc[RW][4] = {};
    for (int kt = 0; kt < 128; kt += 32) {
        for (int l = t; l < 512; l += 256) {
            int row = l >> 3, kq = (l & 7) << 2;
            float4 a = *(const float4*)&A[(size_t)(r0 + row) * 128 + kt + kq];
            sA[kq + 0][row] = a.x; sA[kq + 1][row] = a.y;
            sA[kq + 2][row] = a.z; sA[kq + 3][row] = a.w;
        }
        for (int l = t; l < 32 * M / 4; l += 256) {
            int kk = (l * 4) / M, cc = (l * 4) % M;
            *(float4*)&sW[kk][cc] = *(const float4*)&W[(size_t)(kt + kk) * M + cc];
        }
        __syncthreads();
#pragma unroll
        for (int k = 0; k < 32; k++) {
            float4 w = *(float4*)&sW[k][tx * 4];
            float ar[RW];
#pragma unroll
            for (int i = 0; i < RW; i += 4) {
                float4 a = *(float4*)&sA[k][ty * RW + i];
                ar[i] = a.x; ar[i + 1] = a.y; ar[i + 2] = a.z; ar[i + 3] = a.w;
            }
#pragma unroll
            for (int i = 0; i < RW; i++) {
                acc[i][0] += ar[i] * w.x; acc[i][1] += ar[i] * w.y;
                acc[i][2] += ar[i] * w.z; acc[i][3] += ar[i] * w.w;
            }
        }
        __syncthreads();
    }
    float4 b = *(const float4*)&bias[tx * 4];
#pragma unroll
    for (int i = 0; i < RW; i++) {
        float4 v;
        v.x = acc[i][0] + b.x; v.y = acc[i][1] + b.y;
        v.z = acc[i][2] + b.z; v.w = acc[i][3] + b.w;
        *(float4*)&out[(size_t)(r0 + ty * RW + i) * M + tx * 4] = v;
    }
}

// ---------------- Fused per-dst GATv2 aggregation (CSR, zero atomics) ----------------
// One wave per dst node. Per incoming edge: ee = ea@We (We cols in registers),
// logit via xor-shuffle reduce, ex = exp(logit), acc += ex*xl[src], den += ex.
// Epilogue: out = acc/den + bias (+relu). Softmax max-subtraction skipped (scale-invariant).
template <int H, bool RELU>
__global__ __launch_bounds__(256) void k_agg(const float* __restrict__ xl, const float* __restrict__ xr,
                                             const float* __restrict__ ea, const int2* __restrict__ elist,
                                             const int* __restrict__ row_ptr, const int* __restrict__ deg,
                                             const float* __restrict__ We, const float* __restrict__ att,
                                             const float* __restrict__ bias, float* __restrict__ out, int N) {
    constexpr int HC = H * 64;
    int tid = threadIdx.x, wv = tid >> 6, lane = tid & 63;
    float rWe0[32], rWe1[H == 2 ? 32 : 1];
#pragma unroll
    for (int k = 0; k < 32; k++) rWe0[k] = We[k * HC + lane];
    if constexpr (H == 2) {
#pragma unroll
        for (int k = 0; k < 32; k++) rWe1[k] = We[k * HC + 64 + lane];
    }
    float att0 = att[lane], b0 = bias[lane];
    float att1 = 0.f, b1 = 0.f;
    if constexpr (H == 2) { att1 = att[64 + lane]; b1 = bias[64 + lane]; }
    int n = blockIdx.x * 4 + wv;
    if (n >= N) return;
    int start = row_ptr[n], d = deg[n];
    float xr0 = xr[(size_t)n * HC + lane];
    float xr1 = (H == 2) ? xr[(size_t)n * HC + 64 + lane] : 0.f;
    float acc0 = 0.f, acc1 = 0.f, den0 = 0.f, den1 = 0.f;
    for (int j = 0; j < d; j++) {
        int2 sp = elist[start + j];
        const float4* eap = (const float4*)(ea + (size_t)sp.y * 32);
        const float* xls = xl + (size_t)sp.x * HC;
        float xl0 = xls[lane];
        float xl1 = (H == 2) ? xls[64 + lane] : 0.f;
        float ee0 = 0.f, ee1 = 0.f;
#pragma unroll
        for (int kq = 0; kq < 8; kq++) {
            float4 v = eap[kq];
            ee0 = fmaf(v.x, rWe0[kq * 4 + 0], ee0);
            ee0 = fmaf(v.y, rWe0[kq * 4 + 1], ee0);
            ee0 = fmaf(v.z, rWe0[kq * 4 + 2], ee0);
            ee0 = fmaf(v.w, rWe0[kq * 4 + 3], ee0);
            if constexpr (H == 2) {
                ee1 = fmaf(v.x, rWe1[kq * 4 + 0], ee1);
                ee1 = fmaf(v.y, rWe1[kq * 4 + 1], ee1);
                ee1 = fmaf(v.z, rWe1[kq * 4 + 2], ee1);
                ee1 = fmaf(v.w, rWe1[kq * 4 + 3], ee1);
            }
        }
        float v0 = xl0 + xr0 + ee0;
        v0 = v0 > 0.f ? v0 : 0.2f * v0;
        float p0 = att0 * v0, p1 = 0.f;
        if constexpr (H == 2) {
            float v1 = xl1 + xr1 + ee1;
            v1 = v1 > 0.f ? v1 : 0.2f * v1;
            p1 = att1 * v1;
        }
#pragma unroll
        for (int m = 32; m; m >>= 1) {
            p0 += __shfl_xor(p0, m);
            if constexpr (H == 2) p1 += __shfl_xor(p1, m);
        }
        float ex0 = __expf(p0);
        acc0 = fmaf(ex0, xl0, acc0);
        den0 += ex0;
        if constexpr (H == 2) {
            float ex1 = __expf(p1);
            acc1 = fmaf(ex1, xl1, acc1);
            den1 += ex1;
        }
    }
    float o0 = acc0 / (den0 + 1e-16f) + b0;
    if (RELU) o0 = o0 > 0.f ? o0 : 0.f;
    out[(size_t)n * HC + lane] = o0;
    if constexpr (H == 2) {
        float o1 = acc1 / (den1 + 1e-16f) + b1;
        if (RELU) o1 = o1 > 0.f ? o1 : 0.f;
        out[(size_t)n * HC + 64 + lane] = o1;
    }
}

// ---------------- attentional pooling ----------------
__global__ __launch_bounds__(256) void k_gate(const float* __restrict__ h, const float* __restrict__ G1w,
                                              const float* __restrict__ G1b, const float* __restrict__ G2w,
                                              const float* __restrict__ G2b, const int* __restrict__ batch,
                                              float* __restrict__ gate, float* __restrict__ gden, int N) {
    __shared__ float hr[8][64];
    __shared__ float part[8][2];
    int t = threadIdx.x;
    int n0 = blockIdx.x * 8;
    for (int l = t; l < 8 * 64; l += 256)
        hr[l >> 6][l & 63] = h[(size_t)(n0 + (l >> 6)) * 64 + (l & 63)];
    __syncthreads();
    int c = t & 127, half = t >> 7;
    for (int np = 0; np < 8; np += 2) {
        int n = np + half;
        float acc = G1b[c];
#pragma unroll 8
        for (int k = 0; k < 64; k++) acc += hr[n][k] * G1w[k * 128 + c];
        acc = acc > 0.f ? acc : 0.f;
        float p = acc * G2w[c];
#pragma unroll
        for (int m = 32; m; m >>= 1) p += __shfl_xor(p, m);
        if ((t & 63) == 0) part[n][(t >> 6) & 1] = p;
        __syncthreads();
        if (t < 2) {
            int nn = np + t;
            float gv = __expf(part[nn][0] + part[nn][1] + G2b[0]);
            gate[n0 + nn] = gv;
            atomicAdd(&gden[batch[n0 + nn]], gv);
        }
        __syncthreads();
    }
}

__global__ void k_pool(const float* __restrict__ h, const float* __restrict__ gate,
                       const float* __restrict__ gden, const int* __restrict__ batch,
                       float* __restrict__ pooled, int N) {
    int tid = threadIdx.x;
    int g4 = tid >> 6, lane = tid & 63;
    int n = blockIdx.x * 4 + g4;
    if (n >= N) return;
    int b = batch[n];
    float w = gate[n] / (gden[b] + 1e-16f);
    atomicAdd(&pooled[b * 64 + lane], w * h[(size_t)n * 64 + lane]);
}

__global__ void k_final(const float* __restrict__ pooled, const float* __restrict__ Wreg,
                        const float* __restrict__ breg, float* __restrict__ out) {
    int g = threadIdx.x;
    float acc = breg[0];
    for (int c = 0; c < 64; c++) acc += pooled[g * 64 + c] * Wreg[c];
    out[g] = acc;
}

extern "C" void kernel_launch(void* const* d_in, const int* in_sizes, int n_in,
                              void* d_out, int out_size, void* d_ws, size_t ws_size,
                              hipStream_t stream) {
    const float* x  = (const float*)d_in[0];
    const float* ea = (const float*)d_in[1];
    const int* ei    = (const int*)d_in[2];
    const int* batch = (const int*)d_in[3];
    auto ff = [&](int i) { return (const float*)d_in[i]; };
    const float *W1l = ff(4), *b1l = ff(5), *W1r = ff(6), *b1r = ff(7), *W1e = ff(8),
                *att1 = ff(9), *bias1 = ff(10);
    const float *W2l = ff(11), *b2l = ff(12), *W2r = ff(13), *b2r = ff(14), *W2e = ff(15),
                *att2 = ff(16), *bias2 = ff(17);
    const float *W3l = ff(18), *b3l = ff(19), *W3r = ff(20), *b3r = ff(21), *W3e = ff(22),
                *att3 = ff(23), *bias3 = ff(24);
    const float *G1w = ff(25), *G1b = ff(26), *G2w = ff(27), *G2b = ff(28), *Wreg = ff(29),
                *breg = ff(30);

    const int N = in_sizes[0] / 128;  // 40000
    const int E = in_sizes[2] / 2;    // 640000

    char* ws = (char*)d_ws;
    float* bufA    = (float*)(ws);              // [N,128]
    float* bufB    = (float*)(ws + 20480000);   // [N,128]
    float* bufH    = (float*)(ws + 40960000);   // [N,128]
    int2*  elist   = (int2*)(ws + 61440000);    // [E] (src, edge_id)
    int*   row_ptr = (int*)(ws + 66560000);     // [N]
    int*   deg     = (int*)(ws + 66720000);     // [N]
    int*   cursor  = (int*)(ws + 66880000);     // [N]
    int*   excl    = (int*)(ws + 67040000);     // [N]
    int*   parts   = (int*)(ws + 67200000);     // [<=256]
    float* gate    = (float*)(ws + 67204096);   // [N]
    float* gden    = (float*)(ws + 67364096);   // [64] (pooled follows contiguously)
    float* pooled  = (float*)(ws + 67364352);   // [64,64]

    auto cdiv = [](int a, int b) { return (a + b - 1) / b; };
    const int NB = cdiv(N, 256);
    const dim3 gemmG(N / 64, 2);
    const int AGGB = cdiv(N, 4);

    // ---- CSR build (once; graph shared by all 3 layers) ----
    k_fill<<<NB, 256, 0, stream>>>((unsigned*)deg, N, 0u);
    k_hist<<<cdiv(E, 256), 256, 0, stream>>>(ei, E, deg);
    k_scan_blocks<<<NB, 256, 0, stream>>>(deg, N, excl, parts);
    k_scan_parts<<<1, 256, 0, stream>>>(parts, NB);
    k_scan_add<<<NB, 256, 0, stream>>>(excl, parts, row_ptr, cursor, N);
    k_scatter<<<cdiv(E, 256), 256, 0, stream>>>(ei, E, cursor, elist);

    // ---- layer 1: x -> H=2,C=64, relu ----
    k_gemm2<128, 8><<<gemmG, 256, 0, stream>>>(x, W1l, b1l, W1r, b1r, bufA, bufB);
    k_agg<2, true><<<AGGB, 256, 0, stream>>>(bufA, bufB, ea, elist, row_ptr, deg, W1e, att1, bias1, bufH, N);

    // ---- layer 2: bufH -> H=2,C=64, relu ----
    k_gemm2<128, 8><<<gemmG, 256, 0, stream>>>(bufH, W2l, b2l, W2r, b2r, bufA, bufB);
    k_agg<2, true><<<AGGB, 256, 0, stream>>>(bufA, bufB, ea, elist, row_ptr, deg, W2e, att2, bias2, bufH, N);

    // ---- layer 3: bufH -> H=1,C=64 ----
    k_gemm2<64, 4><<<gemmG, 256, 0, stream>>>(bufH, W3l, b3l, W3r, b3r, bufA, bufB);
    k_agg<1, false><<<AGGB, 256, 0, stream>>>(bufA, bufB, ea, elist, row_ptr, deg, W3e, att3, bias3, bufH, N);

    // ---- attentional pooling + regressor ----
    k_fill<<<cdiv(64 + 64 * 64, 256), 256, 0, stream>>>((unsigned*)gden, 64 + 64 * 64, 0u);
    k_gate<<<N / 8, 256, 0, stream>>>(bufH, G1w, G1b, G2w, G2b, batch, gate, gden, N);
    k_pool<<<AGGB, 256, 0, stream>>>(bufH, gate, gden, batch, pooled, N);
    k_final<<<1, 64, 0, stream>>>(pooled, Wreg, breg, (float*)d_out);
}

// Round 5
// 1068.846 us; speedup vs baseline: 3.0056x; 1.4415x over previous
//
#include <hip/hip_runtime.h>

__global__ void k_fill(unsigned* p, int n, unsigned v) {
    int i = blockIdx.x * blockDim.x + threadIdx.x;
    if (i < n) p[i] = v;
}

// ---------------- CSR build (graph identical across layers; built once) ----------------
__global__ void k_hist(const int* __restrict__ ei, int E, int* __restrict__ deg) {
    int e = blockIdx.x * blockDim.x + threadIdx.x;
    if (e < E) atomicAdd(&deg[ei[E + e]], 1);
}

__global__ void k_scan_blocks(const int* __restrict__ deg, int N,
                              int* __restrict__ excl, int* __restrict__ parts) {
    __shared__ int s[256];
    int t = threadIdx.x, i = blockIdx.x * 256 + t;
    int v = (i < N) ? deg[i] : 0;
    s[t] = v;
    __syncthreads();
    int acc = v;
    for (int off = 1; off < 256; off <<= 1) {
        int add = (t >= off) ? s[t - off] : 0;
        __syncthreads();
        acc += add;
        s[t] = acc;
        __syncthreads();
    }
    if (i < N) excl[i] = acc - v;
    if (t == 255) parts[blockIdx.x] = acc;
}

__global__ void k_scan_parts(int* __restrict__ parts, int nb) {
    __shared__ int s[256];
    int t = threadIdx.x;
    int v = (t < nb) ? parts[t] : 0;
    s[t] = v;
    __syncthreads();
    int acc = v;
    for (int off = 1; off < 256; off <<= 1) {
        int add = (t >= off) ? s[t - off] : 0;
        __syncthreads();
        acc += add;
        s[t] = acc;
        __syncthreads();
    }
    if (t < nb) parts[t] = acc - v;
}

__global__ void k_scan_add(const int* __restrict__ excl, const int* __restrict__ parts,
                           int* __restrict__ row_ptr, int* __restrict__ cursor, int N) {
    int i = blockIdx.x * blockDim.x + threadIdx.x;
    if (i >= N) return;
    int r = excl[i] + parts[i >> 8];
    row_ptr[i] = r;
    cursor[i] = r;
}

__global__ void k_scatter(const int* __restrict__ ei, int E, int* __restrict__ cursor,
                          int2* __restrict__ elist) {
    int e = blockIdx.x * blockDim.x + threadIdx.x;
    if (e >= E) return;
    int d = ei[E + e];
    int j = atomicAdd(&cursor[d], 1);
    elist[j] = make_int2(ei[e], e);
}

// permute edge_attr into CSR order: ea_s[j] = ea[elist[j].y]  (8 threads per edge)
__global__ void k_reorder(const int2* __restrict__ elist, const float* __restrict__ ea, int E,
                          float4* __restrict__ ea_s) {
    int idx = blockIdx.x * blockDim.x + threadIdx.x;
    int j = idx >> 3, q = idx & 7;
    if (j >= E) return;
    ea_s[(size_t)j * 8 + q] = ((const float4*)ea)[(size_t)elist[j].y * 8 + q];
}

// ---------------- Dual GEMM: out{l,r} = A @ W{l,r} + b{l,r} ----------------
template <int M, int RW>
__global__ __launch_bounds__(256) void k_gemm2(const float* __restrict__ A,
                                               const float* __restrict__ Wl, const float* __restrict__ bl,
                                               const float* __restrict__ Wr, const float* __restrict__ br,
                                               float* __restrict__ outl, float* __restrict__ outr) {
    constexpr int TX = M / 4;
    __shared__ float sA[32][68];
    __shared__ float sW[32][M];
    const float* W    = blockIdx.y ? Wr : Wl;
    const float* bias = blockIdx.y ? br : bl;
    float* out        = blockIdx.y ? outr : outl;
    int t = threadIdx.x;
    int tx = t % TX, ty = t / TX;
    int r0 = blockIdx.x * 64;
    float acc[RW][4] = {};
    for (int kt = 0; kt < 128; kt += 32) {
        for (int l = t; l < 512; l += 256) {
            int row = l >> 3, kq = (l & 7) << 2;
            float4 a = *(const float4*)&A[(size_t)(r0 + row) * 128 + kt + kq];
            sA[kq + 0][row] = a.x; sA[kq + 1][row] = a.y;
            sA[kq + 2][row] = a.z; sA[kq + 3][row] = a.w;
        }
        for (int l = t; l < 32 * M / 4; l += 256) {
            int kk = (l * 4) / M, cc = (l * 4) % M;
            *(float4*)&sW[kk][cc] = *(const float4*)&W[(size_t)(kt + kk) * M + cc];
        }
        __syncthreads();
#pragma unroll
        for (int k = 0; k < 32; k++) {
            float4 w = *(float4*)&sW[k][tx * 4];
            float ar[RW];
#pragma unroll
            for (int i = 0; i < RW; i += 4) {
                float4 a = *(float4*)&sA[k][ty * RW + i];
                ar[i] = a.x; ar[i + 1] = a.y; ar[i + 2] = a.z; ar[i + 3] = a.w;
            }
#pragma unroll
            for (int i = 0; i < RW; i++) {
                acc[i][0] += ar[i] * w.x; acc[i][1] += ar[i] * w.y;
                acc[i][2] += ar[i] * w.z; acc[i][3] += ar[i] * w.w;
            }
        }
        __syncthreads();
    }
    float4 b = *(const float4*)&bias[tx * 4];
#pragma unroll
    for (int i = 0; i < RW; i++) {
        float4 v;
        v.x = acc[i][0] + b.x; v.y = acc[i][1] + b.y;
        v.z = acc[i][2] + b.z; v.w = acc[i][3] + b.w;
        *(float4*)&out[(size_t)(r0 + ty * RW + i) * M + tx * 4] = v;
    }
}

// ---------------- Fused per-dst GATv2 aggregation (CSR, zero atomics) ----------------
// SORTED: edge features pre-permuted to CSR order (sequential reads).
template <int H, bool RELU, bool SORTED>
__global__ __launch_bounds__(256) void k_agg(const float* __restrict__ xl, const float* __restrict__ xr,
                                             const float* __restrict__ ea, const float4* __restrict__ ea_s,
                                             const int2* __restrict__ elist,
                                             const int* __restrict__ row_ptr, const int* __restrict__ deg,
                                             const float* __restrict__ We, const float* __restrict__ att,
                                             const float* __restrict__ bias, float* __restrict__ out, int N) {
    constexpr int HC = H * 64;
    int tid = threadIdx.x, wv = tid >> 6, lane = tid & 63;
    float rWe0[32], rWe1[H == 2 ? 32 : 1];
#pragma unroll
    for (int k = 0; k < 32; k++) rWe0[k] = We[k * HC + lane];
    if constexpr (H == 2) {
#pragma unroll
        for (int k = 0; k < 32; k++) rWe1[k] = We[k * HC + 64 + lane];
    }
    float att0 = att[lane], b0 = bias[lane];
    float att1 = 0.f, b1 = 0.f;
    if constexpr (H == 2) { att1 = att[64 + lane]; b1 = bias[64 + lane]; }
    int n = blockIdx.x * 4 + wv;
    if (n >= N) return;
    int start = row_ptr[n], d = deg[n];
    float xr0 = xr[(size_t)n * HC + lane];
    float xr1 = (H == 2) ? xr[(size_t)n * HC + 64 + lane] : 0.f;
    float acc0 = 0.f, acc1 = 0.f, den0 = 0.f, den1 = 0.f;
    for (int j = 0; j < d; j++) {
        int2 sp = elist[start + j];
        const float4* eap = SORTED ? (ea_s + (size_t)(start + j) * 8)
                                   : (const float4*)(ea + (size_t)sp.y * 32);
        const float* xls = xl + (size_t)sp.x * HC;
        float xl0 = xls[lane];
        float xl1 = (H == 2) ? xls[64 + lane] : 0.f;
        float ee0 = 0.f, ee1 = 0.f;
#pragma unroll
        for (int kq = 0; kq < 8; kq++) {
            float4 v = eap[kq];
            ee0 = fmaf(v.x, rWe0[kq * 4 + 0], ee0);
            ee0 = fmaf(v.y, rWe0[kq * 4 + 1], ee0);
            ee0 = fmaf(v.z, rWe0[kq * 4 + 2], ee0);
            ee0 = fmaf(v.w, rWe0[kq * 4 + 3], ee0);
            if constexpr (H == 2) {
                ee1 = fmaf(v.x, rWe1[kq * 4 + 0], ee1);
                ee1 = fmaf(v.y, rWe1[kq * 4 + 1], ee1);
                ee1 = fmaf(v.z, rWe1[kq * 4 + 2], ee1);
                ee1 = fmaf(v.w, rWe1[kq * 4 + 3], ee1);
            }
        }
        float v0 = xl0 + xr0 + ee0;
        v0 = v0 > 0.f ? v0 : 0.2f * v0;
        float p0 = att0 * v0, p1 = 0.f;
        if constexpr (H == 2) {
            float v1 = xl1 + xr1 + ee1;
            v1 = v1 > 0.f ? v1 : 0.2f * v1;
            p1 = att1 * v1;
        }
#pragma unroll
        for (int m = 32; m; m >>= 1) {
            p0 += __shfl_xor(p0, m);
            if constexpr (H == 2) p1 += __shfl_xor(p1, m);
        }
        float ex0 = __expf(p0);
        acc0 = fmaf(ex0, xl0, acc0);
        den0 += ex0;
        if constexpr (H == 2) {
            float ex1 = __expf(p1);
            acc1 = fmaf(ex1, xl1, acc1);
            den1 += ex1;
        }
    }
    float o0 = acc0 / (den0 + 1e-16f) + b0;
    if (RELU) o0 = o0 > 0.f ? o0 : 0.f;
    out[(size_t)n * HC + lane] = o0;
    if constexpr (H == 2) {
        float o1 = acc1 / (den1 + 1e-16f) + b1;
        if (RELU) o1 = o1 > 0.f ? o1 : 0.f;
        out[(size_t)n * HC + 64 + lane] = o1;
    }
}

// ---------------- gate MLP: gate[n] = exp(relu(h[n]@G1w+G1b)@G2w + G2b) ----------------
// 64 nodes per block. h tile in LDS (broadcast reads), G1w column per thread in registers.
// No atomics; per-graph denominator computed in k_pool.
__global__ __launch_bounds__(256) void k_gate(const float* __restrict__ h, const float* __restrict__ G1w,
                                              const float* __restrict__ G1b, const float* __restrict__ G2w,
                                              const float* __restrict__ G2b,
                                              float* __restrict__ gate, int N) {
    __shared__ float sH[64][64];
    __shared__ float part[64][2];
    int t = threadIdx.x;
    int n0 = blockIdx.x * 64;
    for (int l = t; l < 1024; l += 256) {
        float4 v = ((const float4*)(h + (size_t)n0 * 64))[l];
        int n = l >> 4, kq = (l & 15) << 2;
        *(float4*)&sH[n][kq] = v;
    }
    int c = t & 127, half = t >> 7;
    float rW[64];
#pragma unroll
    for (int k = 0; k < 64; k++) rW[k] = G1w[k * 128 + c];
    float g1b = G1b[c], g2w = G2w[c];
    __syncthreads();
    for (int nn = 0; nn < 32; nn++) {
        int n = half * 32 + nn;
        float acc = g1b;
#pragma unroll
        for (int k = 0; k < 64; k += 4) {
            float4 hv = *(const float4*)&sH[n][k];
            acc = fmaf(hv.x, rW[k], acc);
            acc = fmaf(hv.y, rW[k + 1], acc);
            acc = fmaf(hv.z, rW[k + 2], acc);
            acc = fmaf(hv.w, rW[k + 3], acc);
        }
        acc = acc > 0.f ? acc : 0.f;
        float p = acc * g2w;
#pragma unroll
        for (int m = 32; m; m >>= 1) p += __shfl_xor(p, m);
        if ((t & 63) == 0) part[n][(t >> 6) & 1] = p;
    }
    __syncthreads();
    if (t < 64) gate[n0 + t] = __expf(part[t][0] + part[t][1] + G2b[0]);
}

// ---------------- pooling: one block per graph (batch sorted -> binary search range) ----------------
__global__ __launch_bounds__(256) void k_pool(const float* __restrict__ h, const float* __restrict__ gate,
                                              const int* __restrict__ batch,
                                              float* __restrict__ pooled, int N) {
    int g = blockIdx.x;
    int lo = 0, hi = N;
    while (lo < hi) { int mid = (lo + hi) >> 1; if (batch[mid] < g) lo = mid + 1; else hi = mid; }
    int start = lo;
    lo = 0; hi = N;
    while (lo < hi) { int mid = (lo + hi) >> 1; if (batch[mid] < g + 1) lo = mid + 1; else hi = mid; }
    int end = lo;
    int t = threadIdx.x, wv = t >> 6, lane = t & 63;
    float acc = 0.f, den = 0.f;
    for (int n = start + wv; n < end; n += 4) {
        float gv = gate[n];
        acc = fmaf(gv, h[(size_t)n * 64 + lane], acc);
        den += gv;   // same across lanes of this wave
    }
    __shared__ float sacc[4][64];
    __shared__ float sden[4];
    sacc[wv][lane] = acc;
    if (lane == 0) sden[wv] = den;
    __syncthreads();
    if (wv == 0) {
        float a = sacc[0][lane] + sacc[1][lane] + sacc[2][lane] + sacc[3][lane];
        float d = sden[0] + sden[1] + sden[2] + sden[3] + 1e-16f;
        pooled[g * 64 + lane] = a / d;
    }
}

__global__ void k_final(const float* __restrict__ pooled, const float* __restrict__ Wreg,
                        const float* __restrict__ breg, float* __restrict__ out) {
    int g = threadIdx.x;
    float acc = breg[0];
    for (int c = 0; c < 64; c++) acc += pooled[g * 64 + c] * Wreg[c];
    out[g] = acc;
}

extern "C" void kernel_launch(void* const* d_in, const int* in_sizes, int n_in,
                              void* d_out, int out_size, void* d_ws, size_t ws_size,
                              hipStream_t stream) {
    const float* x  = (const float*)d_in[0];
    const float* ea = (const float*)d_in[1];
    const int* ei    = (const int*)d_in[2];
    const int* batch = (const int*)d_in[3];
    auto ff = [&](int i) { return (const float*)d_in[i]; };
    const float *W1l = ff(4), *b1l = ff(5), *W1r = ff(6), *b1r = ff(7), *W1e = ff(8),
                *att1 = ff(9), *bias1 = ff(10);
    const float *W2l = ff(11), *b2l = ff(12), *W2r = ff(13), *b2r = ff(14), *W2e = ff(15),
                *att2 = ff(16), *bias2 = ff(17);
    const float *W3l = ff(18), *b3l = ff(19), *W3r = ff(20), *b3r = ff(21), *W3e = ff(22),
                *att3 = ff(23), *bias3 = ff(24);
    const float *G1w = ff(25), *G1b = ff(26), *G2w = ff(27), *G2b = ff(28), *Wreg = ff(29),
                *breg = ff(30);

    const int N = in_sizes[0] / 128;  // 40000
    const int E = in_sizes[2] / 2;    // 640000

    char* ws = (char*)d_ws;
    float*  bufA    = (float*)(ws);              // [N,128]
    float*  bufB    = (float*)(ws + 20480000);   // [N,128]
    float*  bufH    = (float*)(ws + 40960000);   // [N,128]
    int2*   elist   = (int2*)(ws + 61440000);    // [E] (src, edge_id)
    int*    row_ptr = (int*)(ws + 66560000);     // [N]
    int*    deg     = (int*)(ws + 66720000);     // [N]
    int*    cursor  = (int*)(ws + 66880000);     // [N]
    int*    excl    = (int*)(ws + 67040000);     // [N]
    int*    parts   = (int*)(ws + 67200000);     // [<=256]
    float*  gate    = (float*)(ws + 67204096);   // [N]
    float*  pooled  = (float*)(ws + 67364096);   // [64,64]
    float4* ea_s    = (float4*)(ws + 67380480);  // [E,32] floats, CSR-ordered (optional)
    const bool sorted_ea = ws_size >= (size_t)67380480 + (size_t)E * 32 * 4;

    auto cdiv = [](int a, int b) { return (a + b - 1) / b; };
    const int NB = cdiv(N, 256);
    const dim3 gemmG(N / 64, 2);
    const int AGGB = cdiv(N, 4);

    // ---- CSR build (once; graph shared by all 3 layers) ----
    k_fill<<<NB, 256, 0, stream>>>((unsigned*)deg, N, 0u);
    k_hist<<<cdiv(E, 256), 256, 0, stream>>>(ei, E, deg);
    k_scan_blocks<<<NB, 256, 0, stream>>>(deg, N, excl, parts);
    k_scan_parts<<<1, 256, 0, stream>>>(parts, NB);
    k_scan_add<<<NB, 256, 0, stream>>>(excl, parts, row_ptr, cursor, N);
    k_scatter<<<cdiv(E, 256), 256, 0, stream>>>(ei, E, cursor, elist);
    if (sorted_ea)
        k_reorder<<<cdiv(E * 8, 256), 256, 0, stream>>>(elist, ea, E, ea_s);

    // ---- layer 1 ----
    k_gemm2<128, 8><<<gemmG, 256, 0, stream>>>(x, W1l, b1l, W1r, b1r, bufA, bufB);
    if (sorted_ea)
        k_agg<2, true, true><<<AGGB, 256, 0, stream>>>(bufA, bufB, ea, ea_s, elist, row_ptr, deg, W1e, att1, bias1, bufH, N);
    else
        k_agg<2, true, false><<<AGGB, 256, 0, stream>>>(bufA, bufB, ea, ea_s, elist, row_ptr, deg, W1e, att1, bias1, bufH, N);

    // ---- layer 2 ----
    k_gemm2<128, 8><<<gemmG, 256, 0, stream>>>(bufH, W2l, b2l, W2r, b2r, bufA, bufB);
    if (sorted_ea)
        k_agg<2, true, true><<<AGGB, 256, 0, stream>>>(bufA, bufB, ea, ea_s, elist, row_ptr, deg, W2e, att2, bias2, bufH, N);
    else
        k_agg<2, true, false><<<AGGB, 256, 0, stream>>>(bufA, bufB, ea, ea_s, elist, row_ptr, deg, W2e, att2, bias2, bufH, N);

    // ---- layer 3 ----
    k_gemm2<64, 4><<<gemmG, 256, 0, stream>>>(bufH, W3l, b3l, W3r, b3r, bufA, bufB);
    if (sorted_ea)
        k_agg<1, false, true><<<AGGB, 256, 0, stream>>>(bufA, bufB, ea, ea_s, elist, row_ptr, deg, W3e, att3, bias3, bufH, N);
    else
        k_agg<1, false, false><<<AGGB, 256, 0, stream>>>(bufA, bufB, ea, ea_s, elist, row_ptr, deg, W3e, att3, bias3, bufH, N);

    // ---- attentional pooling + regressor ----
    k_gate<<<N / 64, 256, 0, stream>>>(bufH, G1w, G1b, G2w, G2b, gate, N);
    k_pool<<<64, 256, 0, stream>>>(bufH, gate, batch, pooled, N);
    k_final<<<1, 64, 0, stream>>>(pooled, Wreg, breg, (float*)d_out);
}